// Round 10
// baseline (1282.701 us; speedup 1.0000x reference)
//
#include <hip/hip_runtime.h>

// ---------------------------------------------------------------------------
// MiniGRU fused kernel for MI355X (gfx950) — round 6 design (resubmit r10).
//   tokens = [stoch|action] @ proj_w + proj_b          (K=144 padded to 160)
//   parts  = LN( [tokens|deter] @ core_w ) ; gates ; out = u*c + (1-u)*deter
// Split-fp16 MFMA (hi/lo, lo scaled x2048 to dodge fp16-denorm flush),
// NO workspace usage (round-5 post-timing divergence implicated OOB ws
// writes corrupting neighbor buffers), BM=32, 64 KiB LDS -> 2 WGs/CU.
// ---------------------------------------------------------------------------

typedef _Float16 f16x8 __attribute__((ext_vector_type(8)));
typedef _Float16 f16x4 __attribute__((ext_vector_type(4)));
typedef float    f32x4 __attribute__((ext_vector_type(4)));

#define MFMA16(a, b, c) __builtin_amdgcn_mfma_f32_16x16x32_f16((a), (b), (c), 0, 0, 0)

#define LO_SCALE 2048.0f
#define LO_INV   (1.0f / 2048.0f)

__device__ __forceinline__ float sigmoid_f(float x) {
  return 1.0f / (1.0f + __expf(-x));
}
__device__ __forceinline__ float tanh_f(float x) {
  float ax = fabsf(x);
  float t = 1.0f - 2.0f / (__expf(2.0f * ax) + 1.0f);
  return copysignf(t, x);
}

// 8 waves; wave w owns gate cols [w*32, w*32+32) -> part col-tiles
// {2w,2w+1, 16+2w,16+2w+1, 32+2w,32+2w+1}. Block covers 32 rows.
// LDS: X2h plane [32][512] f16 at 0 (XOR-swizzled rows), X2l at +32768.
// lo-plane values are pre-scaled by 2048 (exact: power-of-2, residual exact
// in fp32) so they sit in fp16 normal range; cross-product MFMAs accumulate
// into a tmp acc that is folded back with *1/2048.
__launch_bounds__(512, 4)
__global__ void minigru_fused(const float* __restrict__ deter,
                              const float* __restrict__ stoch,
                              const float* __restrict__ action,
                              const float* __restrict__ proj_w,
                              const float* __restrict__ proj_b,
                              const float* __restrict__ core_w,
                              const float* __restrict__ ln_g,
                              const float* __restrict__ ln_b,
                              float* __restrict__ out) {
  __shared__ char sm[65536];
  const int tid = threadIdx.x;
  const int lane = tid & 63;
  const int w = tid >> 6;
  const int l15 = lane & 15;
  const int grp = lane >> 4;
  const long row0 = (long)blockIdx.x * 32;

  // swizzled LDS address: row stride 1024B, byte ^= (row&7)<<4
  auto addrH = [&](int row, int kbyte) -> char* {
    return sm + (row << 10) + (kbyte ^ ((row & 7) << 4));
  };
  auto addrL = [&](int row, int kbyte) -> char* {
    return sm + 32768 + (row << 10) + (kbyte ^ ((row & 7) << 4));
  };

  auto stage4 = [&](int r, int kbyte, float4 v) {
    f16x4 h, l;
    _Float16 h0 = (_Float16)v.x; h[0] = h0; l[0] = (_Float16)((v.x - (float)h0) * LO_SCALE);
    _Float16 h1 = (_Float16)v.y; h[1] = h1; l[1] = (_Float16)((v.y - (float)h1) * LO_SCALE);
    _Float16 h2 = (_Float16)v.z; h[2] = h2; l[2] = (_Float16)((v.z - (float)h2) * LO_SCALE);
    _Float16 h3 = (_Float16)v.w; h[3] = h3; l[3] = (_Float16)((v.w - (float)h3) * LO_SCALE);
    *(f16x4*)addrH(r, kbyte) = h;
    *(f16x4*)addrL(r, kbyte) = l;
  };

  // ---- Phase A0: stage [stoch|action] into k' in [256,416) (deter's slot) ----
#pragma unroll
  for (int it = 0; it < 2; ++it) {
    int idx = it * 512 + tid;           // 32 rows x 32 float4
    int r = idx >> 5, c4 = idx & 31;
    stage4(r, 512 + (c4 << 3), ((const float4*)stoch)[(size_t)(row0 + r) * 32 + c4]);
  }
  if (tid < 128) {
    int r = tid >> 2, c4 = tid & 3;     // 32 rows x 4 float4
    stage4(r, 768 + (c4 << 3), ((const float4*)action)[(size_t)(row0 + r) * 4 + c4]);
    f16x4 z;
#pragma unroll
    for (int q = 0; q < 4; ++q) z[q] = (_Float16)0.0f;
    *(f16x4*)addrH(r, 800 + (c4 << 3)) = z;   // zero pad k' [400,416)
    *(f16x4*)addrL(r, 800 + (c4 << 3)) = z;
  }
  __syncthreads();

  // ---- Phase A1: proj GEMM, K=160 (5 kb), each wave 2 token col-tiles ----
  f32x4 accT[2][2];
#pragma unroll
  for (int rt = 0; rt < 2; ++rt)
#pragma unroll
    for (int ci = 0; ci < 2; ++ci)
#pragma unroll
      for (int q = 0; q < 4; ++q) accT[rt][ci][q] = 0.0f;

  for (int kb = 0; kb < 5; ++kb) {
    f16x8 ah[2], al[2];
#pragma unroll
    for (int rt = 0; rt < 2; ++rt) {
      int row = rt * 16 + l15;
      int kbyte = 512 + kb * 64 + grp * 16;   // k' = 256 + kb*32 + grp*8
      ah[rt] = *(const f16x8*)addrH(row, kbyte);
      al[rt] = *(const f16x8*)addrL(row, kbyte);
    }
#pragma unroll
    for (int ci = 0; ci < 2; ++ci) {
      int ct = 2 * w + ci;
      f16x8 bh, bl;
#pragma unroll
      for (int j = 0; j < 8; ++j) {
        int k = kb * 32 + grp * 8 + j;
        float v = (k < 144) ? proj_w[k * 256 + ct * 16 + l15] : 0.0f;
        _Float16 hh = (_Float16)v;
        bh[j] = hh;
        bl[j] = (_Float16)((v - (float)hh) * LO_SCALE);
      }
      f32x4 tmp[2];
#pragma unroll
      for (int rt = 0; rt < 2; ++rt)
#pragma unroll
        for (int q = 0; q < 4; ++q) tmp[rt][q] = 0.0f;
#pragma unroll
      for (int rt = 0; rt < 2; ++rt) {
        accT[rt][ci] = MFMA16(ah[rt], bh, accT[rt][ci]);
        tmp[rt] = MFMA16(al[rt], bh, tmp[rt]);
        tmp[rt] = MFMA16(ah[rt], bl, tmp[rt]);
      }
#pragma unroll
      for (int rt = 0; rt < 2; ++rt)
#pragma unroll
        for (int q = 0; q < 4; ++q) accT[rt][ci][q] += tmp[rt][q] * LO_INV;
    }
  }

  // ---- Phase A2: +proj_b, split, write tokens into X2 k' in [0,256) ----
  // (writes [0,512) bytes; concurrent A1 readers touch only [512,896) — safe)
#pragma unroll
  for (int ci = 0; ci < 2; ++ci) {
    int colb = (2 * w + ci) * 16 + l15;
    float pb = proj_b[colb];
#pragma unroll
    for (int rt = 0; rt < 2; ++rt)
#pragma unroll
      for (int j = 0; j < 4; ++j) {
        int row = rt * 16 + grp * 4 + j;   // C/D layout: col=l15, row=grp*4+j
        float tv = accT[rt][ci][j] + pb;
        _Float16 hh = (_Float16)tv;
        *(_Float16*)addrH(row, 2 * colb) = hh;
        *(_Float16*)addrL(row, 2 * colb) = (_Float16)((tv - (float)hh) * LO_SCALE);
      }
  }
  __syncthreads();

  // ---- Phase B: deter -> k' in [256,512) ----
#pragma unroll
  for (int it = 0; it < 4; ++it) {
    int idx = it * 512 + tid;           // 32 rows x 64 float4
    int r = idx >> 6, c4 = idx & 63;
    stage4(r, 512 + (c4 << 3), ((const float4*)deter)[(size_t)(row0 + r) * 64 + c4]);
  }
  __syncthreads();

  // ---- Phase C: core GEMM, K=512 (16 kb); W fp32 from global, split on fly,
  //      next-step B values prefetched one (kb,ci) step ahead ----
  f32x4 acc[2][6];
#pragma unroll
  for (int rt = 0; rt < 2; ++rt)
#pragma unroll
    for (int ci = 0; ci < 6; ++ci)
#pragma unroll
      for (int q = 0; q < 4; ++q) acc[rt][ci][q] = 0.0f;

  int ctg[6];
#pragma unroll
  for (int ci = 0; ci < 6; ++ci) ctg[ci] = (ci >> 1) * 16 + 2 * w + (ci & 1);

  {
    float bc[8];
#pragma unroll
    for (int j = 0; j < 8; ++j)
      bc[j] = core_w[(grp * 8 + j) * 768 + ctg[0] * 16 + l15];

    for (int kb = 0; kb < 16; ++kb) {
      f16x8 ah[2], al[2];
#pragma unroll
      for (int rt = 0; rt < 2; ++rt) {
        int row = rt * 16 + l15;
        int kbyte = kb * 64 + grp * 16;
        ah[rt] = *(const f16x8*)addrH(row, kbyte);
        al[rt] = *(const f16x8*)addrL(row, kbyte);
      }
#pragma unroll
      for (int ci = 0; ci < 6; ++ci) {
        int kb2 = (ci == 5) ? kb + 1 : kb;
        int ci2 = (ci == 5) ? 0 : ci + 1;
        int kbc = (kb2 < 16) ? kb2 : 15;   // clamp: in-bounds on final step
        float bn[8];
        int nbase = (kbc * 32 + grp * 8) * 768 + ctg[ci2] * 16 + l15;
#pragma unroll
        for (int j = 0; j < 8; ++j) bn[j] = core_w[nbase + j * 768];

        f16x8 bh, bl;
#pragma unroll
        for (int j = 0; j < 8; ++j) {
          _Float16 hh = (_Float16)bc[j];
          bh[j] = hh;
          bl[j] = (_Float16)((bc[j] - (float)hh) * LO_SCALE);
        }
        f32x4 tmp[2];
#pragma unroll
        for (int rt = 0; rt < 2; ++rt)
#pragma unroll
          for (int q = 0; q < 4; ++q) tmp[rt][q] = 0.0f;
#pragma unroll
        for (int rt = 0; rt < 2; ++rt) {
          acc[rt][ci] = MFMA16(ah[rt], bh, acc[rt][ci]);
          tmp[rt] = MFMA16(al[rt], bh, tmp[rt]);
          tmp[rt] = MFMA16(ah[rt], bl, tmp[rt]);
        }
#pragma unroll
        for (int rt = 0; rt < 2; ++rt)
#pragma unroll
          for (int q = 0; q < 4; ++q) acc[rt][ci][q] += tmp[rt][q] * LO_INV;
#pragma unroll
        for (int j = 0; j < 8; ++j) bc[j] = bn[j];
      }
    }
  }
  __syncthreads();   // done reading X2; its LDS space is reused below

  // ---- Phase D: LayerNorm stats over 768 cols/row ----
  float2* red2 = (float2*)sm;             // [8 waves][32 rows]
  float2* ln2 = ((float2*)sm) + 256;      // [32 rows] (mu, rsig)

  float s[2][4], q[2][4];
#pragma unroll
  for (int rt = 0; rt < 2; ++rt)
#pragma unroll
    for (int j = 0; j < 4; ++j) {
      float ss = 0.0f, qq = 0.0f;
#pragma unroll
      for (int ci = 0; ci < 6; ++ci) {
        float v = acc[rt][ci][j];
        ss += v;
        qq += v * v;
      }
      s[rt][j] = ss;
      q[rt][j] = qq;
    }
#pragma unroll
  for (int off = 1; off < 16; off <<= 1) {
#pragma unroll
    for (int rt = 0; rt < 2; ++rt)
#pragma unroll
      for (int j = 0; j < 4; ++j) {
        s[rt][j] += __shfl_xor(s[rt][j], off);
        q[rt][j] += __shfl_xor(q[rt][j], off);
      }
  }
#pragma unroll
  for (int j = 0; j < 4; ++j) {
    if (l15 == j) {
#pragma unroll
      for (int rt = 0; rt < 2; ++rt) {
        float2 p;
        p.x = s[rt][j];
        p.y = q[rt][j];
        red2[w * 32 + rt * 16 + grp * 4 + j] = p;
      }
    }
  }
  __syncthreads();
  if (tid < 32) {
    float ssum = 0.0f, qsum = 0.0f;
#pragma unroll
    for (int ww = 0; ww < 8; ++ww) {
      float2 p = red2[ww * 32 + tid];
      ssum += p.x;
      qsum += p.y;
    }
    float mu = ssum * (1.0f / 768.0f);
    float var = qsum * (1.0f / 768.0f) - mu * mu;
    float2 o;
    o.x = mu;
    o.y = rsqrtf(var + 1e-5f);
    ln2[tid] = o;
  }
  __syncthreads();

  // ---- Phase E: apply LN, gates, store ----
  float gv[6], bv[6];
#pragma unroll
  for (int ci = 0; ci < 6; ++ci) {
    int col = ctg[ci] * 16 + l15;
    gv[ci] = ln_g[col];
    bv[ci] = ln_b[col];
  }
#pragma unroll
  for (int rt = 0; rt < 2; ++rt) {
#pragma unroll
    for (int j = 0; j < 4; ++j) {
      int rowl = rt * 16 + grp * 4 + j;
      float2 mr = ln2[rowl];
      float vals[6];
#pragma unroll
      for (int ci = 0; ci < 6; ++ci)
        vals[ci] = (acc[rt][ci][j] - mr.x) * mr.y * gv[ci] + bv[ci];
#pragma unroll
      for (int p = 0; p < 2; ++p) {
        float rr = sigmoid_f(vals[p]);
        float cc = tanh_f(rr * vals[2 + p]);
        float uu = sigmoid_f(vals[4 + p] - 1.0f);
        int gcol = (2 * w + p) * 16 + l15;
        size_t o = (size_t)(row0 + rowl) * 256 + gcol;
        float dt = deter[o];
        out[o] = uu * cc + (1.0f - uu) * dt;
      }
    }
  }
}

extern "C" void kernel_launch(void* const* d_in, const int* in_sizes, int n_in,
                              void* d_out, int out_size, void* d_ws, size_t ws_size,
                              hipStream_t stream) {
  const float* deter  = (const float*)d_in[0];
  const float* stoch  = (const float*)d_in[1];
  const float* action = (const float*)d_in[2];
  const float* proj_w = (const float*)d_in[3];
  const float* proj_b = (const float*)d_in[4];
  const float* core_w = (const float*)d_in[5];
  const float* ln_g   = (const float*)d_in[6];
  const float* ln_b   = (const float*)d_in[7];
  float* out = (float*)d_out;

  (void)in_sizes; (void)n_in; (void)out_size; (void)d_ws; (void)ws_size;

  minigru_fused<<<dim3(4096), 512, 0, stream>>>(deter, stoch, action,
                                                proj_w, proj_b, core_w,
                                                ln_g, ln_b, out);
}

// Round 12
// 1200.602 us; speedup vs baseline: 1.0684x; 1.0684x over previous
//
#include <hip/hip_runtime.h>

// ---------------------------------------------------------------------------
// MiniGRU fused kernel for MI355X (gfx950) — round 11 design (resubmit r12).
// Round-10 postmortem: VALU-bound (37%) on per-MFMA fp32->fp16 weight split;
// lo-correction proven dead (absmax identical with/without working lo).
// => single-fp16 MFMA (no hi/lo), frag-major fp16 weights prepped in d_ws
//    GUARDED by ws_size (round-5 OOB bug impossible); fallback path converts
//    on the fly if ws is too small. BM=32, 32 KiB LDS, target 4 WG/CU.
// ---------------------------------------------------------------------------

typedef _Float16 f16x8 __attribute__((ext_vector_type(8)));
typedef _Float16 f16x4 __attribute__((ext_vector_type(4)));
typedef float    f32x4 __attribute__((ext_vector_type(4)));

#define MFMA16(a, b, c) __builtin_amdgcn_mfma_f32_16x16x32_f16((a), (b), (c), 0, 0, 0)

// ws layout in _Float16 units: core frags [16kb][48ct][64lane][8], then proj.
#define PF_OFF 393216                   // 16*48*512
#define WS_NEEDED ((size_t)868352)      // (393216 + 5*16*512) * 2 bytes

// core_w [512][768] fp32 -> frag-major fp16.
// elem j of lane(grp*16+l15), tile(kb,ct) = core_w[kb*32+grp*8+j][ct*16+l15]
__global__ void prep_core(const float* __restrict__ cw, _Float16* __restrict__ ws) {
  int t = blockIdx.x * 256 + threadIdx.x;          // 49152 threads
  int l15 = t & 15, grp = (t >> 4) & 3, ctk = t >> 6;  // ctk = kb*48+ct
  int ct = ctk % 48, kb = ctk / 48;
  int n = ct * 16 + l15;
  f16x8 h;
#pragma unroll
  for (int j = 0; j < 8; ++j)
    h[j] = (_Float16)cw[(kb * 32 + grp * 8 + j) * 768 + n];
  ((f16x8*)ws)[t] = h;
}

// proj_w [144][256] fp32 -> frag-major fp16, K padded 144->160 with zeros.
__global__ void prep_proj(const float* __restrict__ pw, _Float16* __restrict__ ws) {
  int t = blockIdx.x * 256 + threadIdx.x;          // 5120 threads
  int l15 = t & 15, grp = (t >> 4) & 3, ctk = t >> 6;  // ctk = kb*16+ct
  int ct = ctk & 15, kb = ctk >> 4;
  int n = ct * 16 + l15;
  f16x8 h;
#pragma unroll
  for (int j = 0; j < 8; ++j) {
    int k = kb * 32 + grp * 8 + j;
    h[j] = (_Float16)((k < 144) ? pw[k * 256 + n] : 0.0f);
  }
  ((f16x8*)(ws + PF_OFF))[t] = h;
}

__device__ __forceinline__ float sigmoid_f(float x) {
  return 1.0f / (1.0f + __expf(-x));
}
__device__ __forceinline__ float tanh_f(float x) {
  float ax = fabsf(x);
  float t = 1.0f - 2.0f / (__expf(2.0f * ax) + 1.0f);
  return copysignf(t, x);
}

// 8 waves; wave w owns gate cols [w*32,w*32+32) -> part col-tiles
// {2w,2w+1, 16+2w,16+2w+1, 32+2w,32+2w+1}. Block covers 32 rows.
// LDS: single fp16 X plane [32][512] (row stride 1024B, XOR-swizzled).
template <bool PREPPED>
__launch_bounds__(512, 8)
__global__ void minigru_main(const float* __restrict__ deter,
                             const float* __restrict__ stoch,
                             const float* __restrict__ action,
                             const float* __restrict__ proj_w,
                             const float* __restrict__ proj_b,
                             const float* __restrict__ core_w,
                             const float* __restrict__ ln_g,
                             const float* __restrict__ ln_b,
                             const _Float16* __restrict__ wf,
                             float* __restrict__ out) {
  __shared__ char sm[32768];
  const int tid = threadIdx.x;
  const int lane = tid & 63;
  const int w = tid >> 6;
  const int l15 = lane & 15;
  const int grp = lane >> 4;
  const long row0 = (long)blockIdx.x * 32;

  auto addrX = [&](int row, int kbyte) -> char* {
    return sm + (row << 10) + (kbyte ^ ((row & 7) << 4));
  };
  auto stage4 = [&](int r, int kbyte, float4 v) {
    f16x4 h;
    h[0] = (_Float16)v.x;
    h[1] = (_Float16)v.y;
    h[2] = (_Float16)v.z;
    h[3] = (_Float16)v.w;
    *(f16x4*)addrX(r, kbyte) = h;
  };

  // ---- A0: stage [stoch|action] into k' [256,416), zero-pad [400,416) ----
#pragma unroll
  for (int it = 0; it < 2; ++it) {
    int idx = it * 512 + tid;            // 32 rows x 32 float4
    int r = idx >> 5, c4 = idx & 31;
    stage4(r, 512 + (c4 << 3), ((const float4*)stoch)[(size_t)(row0 + r) * 32 + c4]);
  }
  if (tid < 128) {
    int r = tid >> 2, c4 = tid & 3;      // 32 rows x 4 float4
    stage4(r, 768 + (c4 << 3), ((const float4*)action)[(size_t)(row0 + r) * 4 + c4]);
    f16x4 z;
#pragma unroll
    for (int q = 0; q < 4; ++q) z[q] = (_Float16)0.0f;
    *(f16x4*)addrX(r, 800 + (c4 << 3)) = z;
  }
  __syncthreads();

  // ---- A1: proj GEMM, K=160 (5 kb), each wave 2 token col-tiles ----
  f32x4 accT[2][2];
#pragma unroll
  for (int rt = 0; rt < 2; ++rt)
#pragma unroll
    for (int ci = 0; ci < 2; ++ci)
#pragma unroll
      for (int q = 0; q < 4; ++q) accT[rt][ci][q] = 0.0f;

  for (int kb = 0; kb < 5; ++kb) {
    f16x8 ah[2];
#pragma unroll
    for (int rt = 0; rt < 2; ++rt)
      ah[rt] = *(const f16x8*)addrX(rt * 16 + l15, 512 + kb * 64 + grp * 16);
#pragma unroll
    for (int ci = 0; ci < 2; ++ci) {
      int ct = 2 * w + ci;
      f16x8 bh;
      if constexpr (PREPPED) {
        bh = ((const f16x8*)(wf + PF_OFF))[(kb * 16 + ct) * 64 + lane];
      } else {
#pragma unroll
        for (int j = 0; j < 8; ++j) {
          int k = kb * 32 + grp * 8 + j;
          bh[j] = (_Float16)((k < 144) ? proj_w[k * 256 + ct * 16 + l15] : 0.0f);
        }
      }
#pragma unroll
      for (int rt = 0; rt < 2; ++rt)
        accT[rt][ci] = MFMA16(ah[rt], bh, accT[rt][ci]);
    }
  }

  // ---- A2: +proj_b, cvt fp16, write tokens into X k' [0,256) ----
  // (writes bytes [0,512); A1 concurrent readers touch only [512,896))
#pragma unroll
  for (int ci = 0; ci < 2; ++ci) {
    int colb = (2 * w + ci) * 16 + l15;
    float pb = proj_b[colb];
#pragma unroll
    for (int rt = 0; rt < 2; ++rt)
#pragma unroll
      for (int j = 0; j < 4; ++j) {
        int row = rt * 16 + grp * 4 + j;  // C/D: col=l15, row=grp*4+j
        *(_Float16*)addrX(row, 2 * colb) = (_Float16)(accT[rt][ci][j] + pb);
      }
  }
  __syncthreads();

  // ---- B: deter -> k' [256,512) ----
#pragma unroll
  for (int it = 0; it < 4; ++it) {
    int idx = it * 512 + tid;            // 32 rows x 64 float4
    int r = idx >> 6, c4 = idx & 63;
    stage4(r, 512 + (c4 << 3), ((const float4*)deter)[(size_t)(row0 + r) * 64 + c4]);
  }
  __syncthreads();

  // ---- C: core GEMM, K=512 (16 kb) ----
  f32x4 acc[2][6];
#pragma unroll
  for (int rt = 0; rt < 2; ++rt)
#pragma unroll
    for (int ci = 0; ci < 6; ++ci)
#pragma unroll
      for (int q = 0; q < 4; ++q) acc[rt][ci][q] = 0.0f;

  int ctg[6];
#pragma unroll
  for (int ci = 0; ci < 6; ++ci) ctg[ci] = (ci >> 1) * 16 + 2 * w + (ci & 1);

  for (int kb = 0; kb < 16; ++kb) {
    f16x8 ah[2];
#pragma unroll
    for (int rt = 0; rt < 2; ++rt)
      ah[rt] = *(const f16x8*)addrX(rt * 16 + l15, kb * 64 + grp * 16);
#pragma unroll
    for (int ci = 0; ci < 6; ++ci) {
      f16x8 bh;
      if constexpr (PREPPED) {
        bh = ((const f16x8*)wf)[(kb * 48 + ctg[ci]) * 64 + lane];
      } else {
        int nbase = (kb * 32 + grp * 8) * 768 + ctg[ci] * 16 + l15;
#pragma unroll
        for (int j = 0; j < 8; ++j)
          bh[j] = (_Float16)core_w[nbase + j * 768];
      }
#pragma unroll
      for (int rt = 0; rt < 2; ++rt)
        acc[rt][ci] = MFMA16(ah[rt], bh, acc[rt][ci]);
    }
  }
  __syncthreads();   // done reading X; LDS reused below

  // ---- D: LayerNorm stats over 768 cols/row ----
  float2* red2 = (float2*)sm;            // [8 waves][32 rows]
  float2* ln2 = ((float2*)sm) + 256;     // [32 rows] (mu, rsig)

#pragma unroll
  for (int rt = 0; rt < 2; ++rt) {
    float s[4], q[4];
#pragma unroll
    for (int j = 0; j < 4; ++j) {
      float ss = 0.0f, qq = 0.0f;
#pragma unroll
      for (int ci = 0; ci < 6; ++ci) {
        float v = acc[rt][ci][j];
        ss += v;
        qq += v * v;
      }
      s[j] = ss;
      q[j] = qq;
    }
#pragma unroll
    for (int off = 1; off < 16; off <<= 1) {
#pragma unroll
      for (int j = 0; j < 4; ++j) {
        s[j] += __shfl_xor(s[j], off);
        q[j] += __shfl_xor(q[j], off);
      }
    }
#pragma unroll
    for (int j = 0; j < 4; ++j) {
      if (l15 == j) {
        float2 p;
        p.x = s[j];
        p.y = q[j];
        red2[w * 32 + rt * 16 + grp * 4 + j] = p;
      }
    }
  }
  __syncthreads();
  if (tid < 32) {
    float ssum = 0.0f, qsum = 0.0f;
#pragma unroll
    for (int ww = 0; ww < 8; ++ww) {
      float2 p = red2[ww * 32 + tid];
      ssum += p.x;
      qsum += p.y;
    }
    float mu = ssum * (1.0f / 768.0f);
    float var = qsum * (1.0f / 768.0f) - mu * mu;
    float2 o;
    o.x = mu;
    o.y = rsqrtf(var + 1e-5f);
    ln2[tid] = o;
  }
  __syncthreads();

  // ---- E: apply LN, gates, store ----
  float gv[6], bv[6];
#pragma unroll
  for (int ci = 0; ci < 6; ++ci) {
    int col = ctg[ci] * 16 + l15;
    gv[ci] = ln_g[col];
    bv[ci] = ln_b[col];
  }
#pragma unroll
  for (int rt = 0; rt < 2; ++rt) {
#pragma unroll
    for (int j = 0; j < 4; ++j) {
      int rowl = rt * 16 + grp * 4 + j;
      float2 mr = ln2[rowl];
      float vals[6];
#pragma unroll
      for (int ci = 0; ci < 6; ++ci)
        vals[ci] = (acc[rt][ci][j] - mr.x) * mr.y * gv[ci] + bv[ci];
#pragma unroll
      for (int p = 0; p < 2; ++p) {
        float rr = sigmoid_f(vals[p]);
        float cc = tanh_f(rr * vals[2 + p]);
        float uu = sigmoid_f(vals[4 + p] - 1.0f);
        int gcol = (2 * w + p) * 16 + l15;
        size_t o = (size_t)(row0 + rowl) * 256 + gcol;
        float dt = deter[o];
        out[o] = uu * cc + (1.0f - uu) * dt;
      }
    }
  }
}

extern "C" void kernel_launch(void* const* d_in, const int* in_sizes, int n_in,
                              void* d_out, int out_size, void* d_ws, size_t ws_size,
                              hipStream_t stream) {
  const float* deter  = (const float*)d_in[0];
  const float* stoch  = (const float*)d_in[1];
  const float* action = (const float*)d_in[2];
  const float* proj_w = (const float*)d_in[3];
  const float* proj_b = (const float*)d_in[4];
  const float* core_w = (const float*)d_in[5];
  const float* ln_g   = (const float*)d_in[6];
  const float* ln_b   = (const float*)d_in[7];
  _Float16* wf = (_Float16*)d_ws;
  float* out = (float*)d_out;

  (void)in_sizes; (void)n_in; (void)out_size;

  if (ws_size >= WS_NEEDED) {
    // fast path: fp16 frag-major weights prepped in ws (bounds-checked above)
    prep_core<<<dim3(192), 256, 0, stream>>>(core_w, wf);
    prep_proj<<<dim3(20), 256, 0, stream>>>(proj_w, wf);
    minigru_main<true><<<dim3(4096), 512, 0, stream>>>(
        deter, stoch, action, proj_w, proj_b, core_w, ln_g, ln_b, wf, out);
  } else {
    // fallback: convert weights on the fly (no ws writes at all)
    minigru_main<false><<<dim3(4096), 512, 0, stream>>>(
        deter, stoch, action, proj_w, proj_b, core_w, ln_g, ln_b, wf, out);
  }
}